// Round 13
// baseline (296.022 us; speedup 1.0000x reference)
//
#include <hip/hip_runtime.h>
#include <hip/hip_bf16.h>

typedef unsigned short u16;
typedef __attribute__((ext_vector_type(8))) short short8;
typedef __attribute__((ext_vector_type(4))) float f32x4;

__device__ __forceinline__ float bf2f(u16 u){
  union { unsigned int i; float f; } c; c.i = ((unsigned int)u) << 16; return c.f;
}
__device__ __forceinline__ u16 f2bf(float f){
  union { float f; unsigned int i; } c; c.f = f;
  unsigned int x = c.i;
  return (u16)((x + 0x7FFFu + ((x >> 16) & 1u)) >> 16);  // RNE
}

// int64-aware edge fetch (values < 2^31, little-endian: low word is the value)
__device__ __forceinline__ int edge_get(const int* __restrict__ e32, int i64, int e, int c){
  int idx = 2 * e + c;
  return i64 ? e32[2 * idx] : e32[idx];
}

// ---------------------------------------------------------------------------
// init_all: ONE dispatch.
//   blocks 0-3 : prep_w for mat=bx (self-detect fp32 flag)
//   block  4   : flags + zero desc[512] (lookback descriptors)
//   blocks 5+  : zero cnt[]
// ---------------------------------------------------------------------------
__global__ __launch_bounds__(256) void init_all(
    const void* __restrict__ Wq, const void* __restrict__ Wk,
    const void* __restrict__ Wv, const void* __restrict__ Wo,
    const void* __restrict__ bq, const void* __restrict__ bk,
    const void* __restrict__ bv, const void* __restrict__ bo,
    u16* __restrict__ Wt, float* __restrict__ biasP,
    const u16* __restrict__ lig16, const int* __restrict__ e32,
    int* __restrict__ flags, int* __restrict__ desc,
    int* __restrict__ cnt, int ntot)
{
  int bx = blockIdx.x, tid = threadIdx.x;

  if (bx < 4){
    __shared__ int Fsh;
    if (tid < 64){
      int c = 0;
      #pragma unroll
      for (int j = 0; j < 4; j++){
        u16 u = lig16[(tid * 4 + j) * 2];
        int ex = (u >> 7) & 0xFF;
        if (ex >= 96 && ex < 160) c++;
      }
      #pragma unroll
      for (int off = 1; off < 64; off <<= 1) c += __shfl_xor(c, off);
      if (tid == 0) Fsh = (c < 128) ? 1 : 0;
    }
    __syncthreads();
    int F = Fsh;
    int mat = bx;
    const void* W = (mat == 0) ? Wq : (mat == 1) ? Wk : (mat == 2) ? Wv : Wo;
    const void* b = (mat == 0) ? bq : (mat == 1) ? bk : (mat == 2) ? bv : bo;
    u16* dst = Wt + mat * 16384;
    #pragma unroll 4
    for (int j = 0; j < 64; j++){
      int idx = tid + j * 256;          // k = idx>>7, n = idx&127
      u16 w = F ? f2bf(((const float*)W)[idx]) : ((const u16*)W)[idx];
      dst[(idx & 127) * 128 + (idx >> 7)] = w;
    }
    if (tid < 128)
      biasP[mat * 128 + tid] = F ? ((const float*)b)[tid] : bf2f(((const u16*)b)[tid]);
  } else if (bx == 4){
    if (tid < 64){
      int c = 0, nz = 0;
      #pragma unroll
      for (int j = 0; j < 4; j++){
        u16 u = lig16[(tid * 4 + j) * 2];
        int ex = (u >> 7) & 0xFF;
        if (ex >= 96 && ex < 160) c++;
        if (e32[(tid * 4 + j) * 2 + 1] != 0) nz++;
      }
      #pragma unroll
      for (int off = 1; off < 64; off <<= 1){
        c  += __shfl_xor(c, off);
        nz += __shfl_xor(nz, off);
      }
      if (tid == 0){
        flags[0] = (c < 128) ? 1 : 0;
        flags[1] = (nz == 0) ? 1 : 0;
      }
    }
    desc[tid] = 0;                      // lookback descriptors: state 0 = invalid
    desc[256 + tid] = 0;
  } else {
    int i = (bx - 5) * 256 + tid;
    if (i < ntot) cnt[i] = 0;
  }
}

// ---------------------------------------------------------------------------
// edge_pre: RBF bias (ebias = attr@Wr + br) + degree count. Runs before QKV
// (degrees gate QKV tiles).
// ---------------------------------------------------------------------------
__global__ __launch_bounds__(256) void edge_pre(
    const void* __restrict__ attr, const void* __restrict__ Wr,
    const void* __restrict__ br, float* __restrict__ ebias,
    const int* __restrict__ edges, const int* __restrict__ ls_p,
    const int* __restrict__ ps_p, int* __restrict__ cnt, int nlig, int E_,
    const int* __restrict__ flags)
{
  __shared__ float w[16][8];
  __shared__ float b[8];
  int tid = threadIdx.x;
  int F = flags[0];
  if (tid < 128) w[tid >> 3][tid & 7] = F ? ((const float*)Wr)[tid] : bf2f(((const u16*)Wr)[tid]);
  if (tid < 8)   b[tid] = F ? ((const float*)br)[tid] : bf2f(((const u16*)br)[tid]);
  __syncthreads();
  int e = blockIdx.x * 256 + tid;
  if (e >= E_) return;

  int I64 = flags[1];
  int dl = edge_get(edges, I64, e, 0) - ls_p[0];
  int dp = edge_get(edges, I64, e, 1) - ps_p[0];
  atomicAdd(&cnt[dl], 1);
  atomicAdd(&cnt[nlig + dp], 1);

  float a[16];
  if (F){
    const float* af = (const float*)attr;
    #pragma unroll
    for (int j = 0; j < 4; j++){
      float4 t = *(const float4*)&af[e * 16 + j * 4];
      a[4*j] = t.x; a[4*j+1] = t.y; a[4*j+2] = t.z; a[4*j+3] = t.w;
    }
  } else {
    const u16* au = (const u16*)attr;
    #pragma unroll
    for (int j = 0; j < 4; j++){
      ushort4 t = *(const ushort4*)&au[e * 16 + j * 4];
      a[4*j] = bf2f(t.x); a[4*j+1] = bf2f(t.y); a[4*j+2] = bf2f(t.z); a[4*j+3] = bf2f(t.w);
    }
  }
  #pragma unroll
  for (int hh = 0; hh < 8; hh++){
    float s = b[hh];
    #pragma unroll
    for (int r = 0; r < 16; r++) s += a[r] * w[r][hh];
    ebias[e * 8 + hh] = s;
  }
}

// ---------------------------------------------------------------------------
// scan_lookback: standalone decoupled-lookback scan (rocPRIM pattern).
// 49 blocks x 2048 nodes; s_sleep backoff. R9: never fuse spinning consumers.
// ---------------------------------------------------------------------------
__global__ __launch_bounds__(256) void scan_lookback(
    const int* __restrict__ cnt, int* __restrict__ offs, int* __restrict__ cursor,
    int* __restrict__ desc, int n)
{
  __shared__ int lds[256];
  __shared__ int base_s;
  int bx = blockIdx.x, tid = threadIdx.x;
  int i0 = bx * 2048 + tid * 8;

  int v[8]; int s = 0;
  #pragma unroll
  for (int j = 0; j < 8; j++){
    int idx = i0 + j;
    v[j] = (idx < n) ? cnt[idx] : 0;
    s += v[j];
  }
  lds[tid] = s; __syncthreads();
  for (int off = 1; off < 256; off <<= 1){
    int t = (tid >= off) ? lds[tid - off] : 0;
    __syncthreads();
    lds[tid] += t;
    __syncthreads();
  }
  int thr_excl = lds[tid] - s;
  int block_sum = lds[255];

  if (tid == 0){
    if (bx == 0){
      __hip_atomic_store(&desc[0], (block_sum << 2) | 2, __ATOMIC_RELEASE,
                         __HIP_MEMORY_SCOPE_AGENT);
      base_s = 0;
    } else {
      __hip_atomic_store(&desc[bx], (block_sum << 2) | 1, __ATOMIC_RELEASE,
                         __HIP_MEMORY_SCOPE_AGENT);
      int running = 0;
      int idx = bx - 1;
      while (true){
        int d;
        while (((d = __hip_atomic_load(&desc[idx], __ATOMIC_ACQUIRE,
                                       __HIP_MEMORY_SCOPE_AGENT)) & 3) == 0){
          __builtin_amdgcn_s_sleep(1);
        }
        running += (d >> 2);
        if ((d & 3) == 2) break;
        idx--;
      }
      __hip_atomic_store(&desc[bx], ((running + block_sum) << 2) | 2,
                         __ATOMIC_RELEASE, __HIP_MEMORY_SCOPE_AGENT);
      base_s = running;
    }
  }
  __syncthreads();

  int base = base_s + thr_excl;
  #pragma unroll
  for (int j = 0; j < 8; j++){
    int idx = i0 + j;
    if (idx < n){
      offs[idx] = base;
      cursor[idx] = base;
      base += v[j];
      if (idx == n - 1) offs[n] = base;
    }
  }
}

// ---------------------------------------------------------------------------
// fat_qkv_sc: QKV projection with ACTIVITY SKIP + scatter, one dispatch.
//   Q role (TT 64-row tiles): skip tile if all rows degree-0 (R12-proven).
//   S role (eb blocks): scatter. R13: payload widened to {src, bias 8xf32} —
//   scatter reads ebias SEQUENTIALLY (by e) and embeds it at the scattered
//   position, so attn's bias read becomes sequential-in-i (was 524k random
//   32-B gathers = up to ~67 MB line traffic in attn).
// ---------------------------------------------------------------------------
__global__ __launch_bounds__(256) void fat_qkv_sc(
    const void* __restrict__ A0, int M0, const void* __restrict__ A1, int M1, int mb0,
    const u16* __restrict__ Wt, const float* __restrict__ biasP,
    u16* __restrict__ O0b, u16* __restrict__ O1b, u16* __restrict__ O2b,
    const int* __restrict__ offs, const float* __restrict__ ebias,
    const int* __restrict__ edges, const int* __restrict__ ls_p,
    const int* __restrict__ ps_p, int* __restrict__ cursor,
    int* __restrict__ sSrc, float* __restrict__ sBias,
    int nlig, int E_, const int* __restrict__ flags)
{
  __shared__ __align__(16) char smem[34816];
  int tid = threadIdx.x;
  int F = flags[0];

  int TT = mb0 + ((M1 + 63) >> 6);
  int eb = (E_ + 255) >> 8;
  int G  = TT + eb;
  int bx = blockIdx.x;
  long long pp = (long long)bx * TT;
  int tile = (int)(pp / G);
  int isQ  = (int)(((long long)(bx + 1) * TT) / G) > tile;

  if (isQ){
    u16 (*As)[136] = (u16(*)[136])smem;
    u16 (*Fs)[136] = (u16(*)[136])(smem + 17408);
    __shared__ int act;
    int AF = F;                               // A dtype: 1=fp32, 0=bf16
    const void* A; int M, m0, orow;
    if (tile < mb0){ A = A0; M = M0; m0 = tile * 64;          orow = m0; }
    else           { A = A1; M = M1; m0 = (tile - mb0) * 64;  orow = M0 + m0; }

    // -------- activity check: any row in tile with degree > 0 ? --------
    if (tid == 0) act = 0;
    __syncthreads();
    if (tid < 64 && m0 + tid < M){
      int r = orow + tid;
      if (offs[r + 1] > offs[r]) act = 1;     // benign same-value race
    }
    __syncthreads();
    if (!act) return;                         // block-uniform exit

    if (AF){
      const float* Af = (const float*)A;
      #pragma unroll
      for (int j = 0; j < 8; j++){
        int u = tid + j * 256, row = u >> 5, c4 = (u & 31) * 4;
        float4 v = make_float4(0.f, 0.f, 0.f, 0.f);
        if (m0 + row < M) v = *(const float4*)&Af[(size_t)(m0 + row) * 128 + c4];
        ushort4 o; o.x = f2bf(v.x); o.y = f2bf(v.y); o.z = f2bf(v.z); o.w = f2bf(v.w);
        *(ushort4*)&As[row][c4] = o;
      }
    } else {
      const float4* Au = (const float4*)A;    // 16 B = 8 bf16
      #pragma unroll
      for (int j = 0; j < 4; j++){
        int u = tid + j * 256, row = u >> 4, c8 = (u & 15);
        float4 v = make_float4(0.f, 0.f, 0.f, 0.f);
        if (m0 + row < M) v = Au[(size_t)(m0 + row) * 16 + c8];
        *(float4*)&As[row][c8 * 8] = v;
      }
    }
    __syncthreads();

    int wave = tid >> 6, lane = tid & 63;
    int quad = lane >> 4, ml = lane & 15;

    for (int mat = 0; mat < 3; mat++){
      const u16* wp = Wt + (size_t)mat * 16384
                        + (size_t)(wave * 32 + ml) * 128 + quad * 8;
      short8 wf0[4], wf1[4];
      #pragma unroll
      for (int kk = 0; kk < 4; kk++){
        wf0[kk] = *(const short8*)&wp[kk * 32];
        wf1[kk] = *(const short8*)&wp[2048 + kk * 32];
      }
      float b0 = biasP[mat * 128 + wave * 32 + ml];
      float b1 = biasP[mat * 128 + wave * 32 + 16 + ml];

      f32x4 acc[4][2];
      #pragma unroll
      for (int mt = 0; mt < 4; mt++){
        acc[mt][0] = (f32x4){0.f, 0.f, 0.f, 0.f};
        acc[mt][1] = (f32x4){0.f, 0.f, 0.f, 0.f};
      }
      #pragma unroll
      for (int mt = 0; mt < 4; mt++){
        #pragma unroll
        for (int kk = 0; kk < 4; kk++){
          short8 af = *(const short8*)&As[mt * 16 + ml][kk * 32 + quad * 8];
          acc[mt][0] = __builtin_amdgcn_mfma_f32_16x16x32_bf16(af, wf0[kk], acc[mt][0], 0, 0, 0);
          acc[mt][1] = __builtin_amdgcn_mfma_f32_16x16x32_bf16(af, wf1[kk], acc[mt][1], 0, 0, 0);
        }
      }

      if (mat > 0) __syncthreads();           // prev mat's Fs store-reads done
      #pragma unroll
      for (int mt = 0; mt < 4; mt++){
        #pragma unroll
        for (int r = 0; r < 4; r++){
          int row = mt * 16 + quad * 4 + r;
          Fs[row][wave * 32 + ml]      = f2bf(acc[mt][0][r] + b0);
          Fs[row][wave * 32 + 16 + ml] = f2bf(acc[mt][1][r] + b1);
        }
      }
      __syncthreads();                        // Fs ready
      u16* Cb = (mat == 0) ? O0b : ((mat == 1) ? O1b : O2b);
      #pragma unroll
      for (int j = 0; j < 4; j++){
        int u = tid + j * 256, row = u >> 4, c8 = (u & 15) * 8;
        if (m0 + row < M)
          *(short8*)&Cb[(size_t)(orow + row) * 128 + c8] = *(const short8*)&Fs[row][c8];
      }
    }
  } else {
    // ---------------- scatter role (src + inline bias payload) ----------------
    int eidx = bx - tile;
    int e = eidx * 256 + tid;
    if (e >= E_) return;
    int I64 = flags[1];
    int dl = edge_get(edges, I64, e, 0) - ls_p[0];
    int dp = edge_get(edges, I64, e, 1) - ps_p[0];
    float4 eb0 = *(const float4*)&ebias[(size_t)e * 8];
    float4 eb1 = *(const float4*)&ebias[(size_t)e * 8 + 4];
    int p1 = atomicAdd(&cursor[dl], 1);
    sSrc[p1] = nlig + dp;
    *(float4*)&sBias[(size_t)p1 * 8]     = eb0;
    *(float4*)&sBias[(size_t)p1 * 8 + 4] = eb1;
    int p2 = atomicAdd(&cursor[nlig + dp], 1);
    sSrc[p2] = dl;
    *(float4*)&sBias[(size_t)p2 * 8]     = eb0;
    *(float4*)&sBias[(size_t)p2 * 8 + 4] = eb1;
  }
}

// ---------------------------------------------------------------------------
// Attention v3: v2 structure (4 edges/wave via quarter-waves, 1 shfl/edge,
// pipelined gathers, butterfly merge) with R13 changes:
//  - bias read sequential-in-i from sBias (was random ebias[eid] gather)
//  - empty nodes return WITHOUT writing AGG (out_proj stages zeros itself)
//  - Q pre-scaled by SCALE at load
// ---------------------------------------------------------------------------
__global__ __launch_bounds__(256) void attn_kernel(
    const u16* __restrict__ Q, const u16* __restrict__ K, const u16* __restrict__ V,
    const int* __restrict__ sSrc, const float* __restrict__ sBias,
    const int* __restrict__ offs, u16* __restrict__ AGG, int ntot)
{
  int t = blockIdx.x * 4 + (threadIdx.x >> 6);
  if (t >= ntot) return;
  int lane = threadIdx.x & 63;
  int ql = lane & 15;
  int q4 = lane >> 4;
  int h  = ql >> 1;

  int beg = offs[t], end = offs[t + 1];
  if (beg == end) return;                // no AGG write: out_proj zero-stages

  short8 qv = *(const short8*)&Q[(size_t)t * 128 + ql * 8];
  float qf[8];
  #pragma unroll
  for (int j = 0; j < 8; j++) qf[j] = bf2f((u16)qv[j]) * 0.25f;  // SCALE folded

  float m = -1e30f, l = 0.f;
  float a[8];
  #pragma unroll
  for (int j = 0; j < 8; j++) a[j] = 0.f;

  int i = beg + q4;
  int cur = 0, nxt = 0;
  if (i < end)     cur = sSrc[i];
  if (i + 4 < end) nxt = sSrc[i + 4];

  short8 kA = {0,0,0,0,0,0,0,0}, vA = {0,0,0,0,0,0,0,0};
  float ebA = 0.f;
  if (i < end){
    kA = *(const short8*)&K[(size_t)cur * 128 + ql * 8];
    vA = *(const short8*)&V[(size_t)cur * 128 + ql * 8];
    ebA = sBias[(size_t)i * 8 + h];
  }

  while (i < end){
    short8 kB = {0,0,0,0,0,0,0,0}, vB = {0,0,0,0,0,0,0,0};
    float ebB = 0.f;
    if (i + 4 < end){
      kB = *(const short8*)&K[(size_t)nxt * 128 + ql * 8];
      vB = *(const short8*)&V[(size_t)nxt * 128 + ql * 8];
      ebB = sBias[(size_t)(i + 4) * 8 + h];
    }
    int n2 = 0;
    if (i + 8 < end) n2 = sSrc[i + 8];

    float s = 0.f;
    #pragma unroll
    for (int j = 0; j < 8; j++) s += qf[j] * bf2f((u16)kA[j]);
    s += __shfl_xor(s, 1);               // pair-sum: full 16-dim head dot
    float logit = s + ebA;               // SCALE already folded into qf
    float nm = fmaxf(m, logit);
    float alpha = __expf(m - nm);
    float p = __expf(logit - nm);
    #pragma unroll
    for (int j = 0; j < 8; j++) a[j] = a[j] * alpha + p * bf2f((u16)vA[j]);
    l = l * alpha + p;
    m = nm;

    kA = kB; vA = vB; ebA = ebB;
    cur = nxt; nxt = n2;
    i += 4;
  }

  #pragma unroll
  for (int mask = 16; mask <= 32; mask <<= 1){
    float mo = __shfl_xor(m, mask);
    float lo = __shfl_xor(l, mask);
    float nm = fmaxf(m, mo);
    float sA = __expf(m - nm);
    float sB = __expf(mo - nm);
    l = l * sA + lo * sB;
    #pragma unroll
    for (int j = 0; j < 8; j++){
      float ao = __shfl_xor(a[j], mask);
      a[j] = a[j] * sA + ao * sB;
    }
    m = nm;
  }

  if (lane < 16){
    float inv = 1.f / (l + 1e-8f);
    short8 o;
    #pragma unroll
    for (int j = 0; j < 8; j++) o[j] = (short)f2bf(a[j] * inv);
    *(short8*)&AGG[(size_t)t * 128 + ql * 8] = o;
  }
}

// ---------------------------------------------------------------------------
// out_proj: AGG @ Wo + bo -> OUT. Bias-only fast path for fully-inactive
// tiles; mixed tiles stage ZEROS for degree-0 rows (attn no longer writes
// zero AGG rows). 64-row tiles, f32 direct store from accumulators.
// ---------------------------------------------------------------------------
__global__ __launch_bounds__(256) void out_proj(
    const u16* __restrict__ AGG, int M, const u16* __restrict__ Wt,
    const float* __restrict__ biasP, void* __restrict__ OUT,
    const int* __restrict__ offs, const int* __restrict__ flags)
{
  __shared__ __align__(16) u16 As[64][136];
  __shared__ __align__(16) u16 Fs[64][136];
  __shared__ int act;
  __shared__ int actRow[64];

  int tid = threadIdx.x;
  int F = flags[0];
  int m0 = blockIdx.x * 64;

  if (tid == 0) act = 0;
  __syncthreads();
  if (tid < 64){
    int r = m0 + tid;
    int a = (r < M) ? (offs[r + 1] > offs[r] ? 1 : 0) : 0;
    actRow[tid] = a;
    if (a) act = 1;                           // benign same-value race
  }
  __syncthreads();

  if (!act){
    // bias-only rows (out = bo exactly)
    if (F){
      float* Of = (float*)OUT;
      #pragma unroll
      for (int j = 0; j < 8; j++){
        int u = tid + j * 256, row = u >> 5, c4 = (u & 31) * 4;
        if (m0 + row < M)
          *(float4*)&Of[(size_t)(m0 + row) * 128 + c4] = *(const float4*)&biasP[384 + c4];
      }
    } else {
      u16* Ob = (u16*)OUT;
      #pragma unroll
      for (int j = 0; j < 4; j++){
        int u = tid + j * 256, row = u >> 4, c8 = (u & 15) * 8;
        if (m0 + row < M){
          short8 s8;
          #pragma unroll
          for (int k = 0; k < 8; k++) s8[k] = (short)f2bf(biasP[384 + c8 + k]);
          *(short8*)&Ob[(size_t)(m0 + row) * 128 + c8] = s8;
        }
      }
    }
    return;
  }

  // stage AGG tile (bf16); zero rows for degree-0 nodes
  {
    const float4* Au = (const float4*)AGG;
    #pragma unroll
    for (int j = 0; j < 4; j++){
      int u = tid + j * 256, row = u >> 4, c8 = (u & 15);
      float4 v = make_float4(0.f, 0.f, 0.f, 0.f);
      if (m0 + row < M && actRow[row]) v = Au[(size_t)(m0 + row) * 16 + c8];
      *(float4*)&As[row][c8 * 8] = v;
    }
  }
  __syncthreads();

  int wave = tid >> 6, lane = tid & 63;
  int quad = lane >> 4, ml = lane & 15;

  const u16* wp = Wt + (size_t)3 * 16384 + (size_t)(wave * 32 + ml) * 128 + quad * 8;
  short8 wf0[4], wf1[4];
  #pragma unroll
  for (int kk = 0; kk < 4; kk++){
    wf0[kk] = *(const short8*)&wp[kk * 32];
    wf1[kk] = *(const short8*)&wp[2048 + kk * 32];
  }
  float b0 = biasP[384 + wave * 32 + ml];
  float b1 = biasP[384 + wave * 32 + 16 + ml];

  f32x4 acc[4][2];
  #pragma unroll
  for (int mt = 0; mt < 4; mt++){
    acc[mt][0] = (f32x4){0.f, 0.f, 0.f, 0.f};
    acc[mt][1] = (f32x4){0.f, 0.f, 0.f, 0.f};
  }
  #pragma unroll
  for (int mt = 0; mt < 4; mt++){
    #pragma unroll
    for (int kk = 0; kk < 4; kk++){
      short8 af = *(const short8*)&As[mt * 16 + ml][kk * 32 + quad * 8];
      acc[mt][0] = __builtin_amdgcn_mfma_f32_16x16x32_bf16(af, wf0[kk], acc[mt][0], 0, 0, 0);
      acc[mt][1] = __builtin_amdgcn_mfma_f32_16x16x32_bf16(af, wf1[kk], acc[mt][1], 0, 0, 0);
    }
  }

  if (F){
    float* Of = (float*)OUT;
    #pragma unroll
    for (int mt = 0; mt < 4; mt++){
      #pragma unroll
      for (int r = 0; r < 4; r++){
        int row = mt * 16 + quad * 4 + r;
        if (m0 + row < M){
          float* op = &Of[(size_t)(m0 + row) * 128 + wave * 32 + ml];
          op[0]  = acc[mt][0][r] + b0;
          op[16] = acc[mt][1][r] + b1;
        }
      }
    }
  } else {
    #pragma unroll
    for (int mt = 0; mt < 4; mt++){
      #pragma unroll
      for (int r = 0; r < 4; r++){
        int row = mt * 16 + quad * 4 + r;
        Fs[row][wave * 32 + ml]      = f2bf(acc[mt][0][r] + b0);
        Fs[row][wave * 32 + 16 + ml] = f2bf(acc[mt][1][r] + b1);
      }
    }
    __syncthreads();
    u16* Ob = (u16*)OUT;
    #pragma unroll
    for (int j = 0; j < 4; j++){
      int u = tid + j * 256, row = u >> 4, c8 = (u & 15) * 8;
      if (m0 + row < M)
        *(short8*)&Ob[(size_t)(m0 + row) * 128 + c8] = *(const short8*)&Fs[row][c8];
    }
  }
}

// ---------------------------------------------------------------------------
extern "C" void kernel_launch(void* const* d_in, const int* in_sizes, int n_in,
                              void* d_out, int out_size, void* d_ws, size_t ws_size,
                              hipStream_t stream)
{
  const void* ligand_x  = d_in[0];
  const void* protein_x = d_in[1];
  const int* edges      = (const int*)d_in[2];
  const void* attr      = d_in[3];
  const void* Wq = d_in[4];  const void* bq = d_in[5];
  const void* Wk = d_in[6];  const void* bk = d_in[7];
  const void* Wv = d_in[8];  const void* bv = d_in[9];
  const void* Wo = d_in[10]; const void* bo = d_in[11];
  const void* Wr = d_in[12]; const void* br = d_in[13];
  const int* ls_p = (const int*)d_in[14];
  const int* ps_p = (const int*)d_in[15];

  const int nlig = in_sizes[0] / 128;
  const int nprot = in_sizes[1] / 128;
  const int E = in_sizes[2] / 2;
  const int ntot = nlig + nprot;

  char* w = (char*)d_ws;
  size_t off = 0;
  auto alloc = [&](size_t bytes) -> void* {
    void* p = w + off;
    off = (off + bytes + 255) & ~(size_t)255;
    return p;
  };
  int*   flags = (int*)alloc(256);
  u16*   Wt    = (u16*)alloc(4 * 16384 * 2);
  float* biasP = (float*)alloc(4 * 128 * 4);
  u16* Qb  = (u16*)alloc((size_t)ntot * 128 * 2);
  u16* Kb  = (u16*)alloc((size_t)ntot * 128 * 2);
  u16* Vb  = (u16*)alloc((size_t)ntot * 128 * 2);
  u16* AGG = (u16*)alloc((size_t)ntot * 128 * 2);
  float* ebias = (float*)alloc((size_t)E * 8 * 4);
  int* cnt    = (int*)alloc((size_t)ntot * 4);
  int* offs   = (int*)alloc((size_t)(ntot + 1) * 4);
  int* cursor = (int*)alloc((size_t)ntot * 4);
  int* desc   = (int*)alloc(512 * 4);
  int*   sSrc  = (int*)alloc((size_t)2 * E * 4);
  float* sBias = (float*)alloc((size_t)2 * E * 8 * 4);
  (void)ws_size; (void)n_in; (void)out_size;

  const int mb_l = (nlig + 63) / 64;
  const int mb_p = (nprot + 63) / 64;
  const int mb_t = (ntot + 63) / 64;
  const int eb = (E + 255) / 256;
  const int nb = (ntot + 255) / 256;
  const int nsb = (ntot + 2047) / 2048;

  // 0. init: prep_w (self-detect) + flags + desc zero + cnt zero
  init_all<<<nb + 5, 256, 0, stream>>>(
      Wq, Wk, Wv, Wo, bq, bk, bv, bo, Wt, biasP,
      (const u16*)ligand_x, edges, flags, desc, cnt, ntot);

  // 1. edge_pre: RBF bias + degree count (degrees gate QKV tiles)
  edge_pre<<<eb, 256, 0, stream>>>(attr, Wr, br, ebias, edges, ls_p, ps_p,
                                   cnt, nlig, E, flags);

  // 2. decoupled-lookback scan -> offs/cursor
  scan_lookback<<<nsb, 256, 0, stream>>>(cnt, offs, cursor, desc, ntot);

  // 3. FAT: QKV (active tiles only) + scatter (src + inline bias)
  const int TT = mb_l + mb_p;
  fat_qkv_sc<<<TT + eb, 256, 0, stream>>>(
      ligand_x, nlig, protein_x, nprot, mb_l,
      Wt, biasP, Qb, Kb, Vb,
      offs, ebias, edges, ls_p, ps_p, cursor, sSrc, sBias, nlig, E, flags);

  // 4. attention -> AGG (active nodes only)
  attn_kernel<<<(ntot + 3) / 4, 256, 0, stream>>>(
      Qb, Kb, Vb, sSrc, sBias, offs, AGG, ntot);

  // 5. output projection (bias-only fast path; zero-stage degree-0 rows)
  out_proj<<<mb_t, 256, 0, stream>>>(AGG, ntot, Wt, biasP, d_out, offs, flags);
}

// Round 14
// 276.702 us; speedup vs baseline: 1.0698x; 1.0698x over previous
//
#include <hip/hip_runtime.h>
#include <hip/hip_bf16.h>

typedef unsigned short u16;
typedef __attribute__((ext_vector_type(8))) short short8;
typedef __attribute__((ext_vector_type(4))) float f32x4;

__device__ __forceinline__ float bf2f(u16 u){
  union { unsigned int i; float f; } c; c.i = ((unsigned int)u) << 16; return c.f;
}
__device__ __forceinline__ u16 f2bf(float f){
  union { float f; unsigned int i; } c; c.f = f;
  unsigned int x = c.i;
  return (u16)((x + 0x7FFFu + ((x >> 16) & 1u)) >> 16);  // RNE
}

// int64-aware edge fetch (values < 2^31, little-endian: low word is the value)
__device__ __forceinline__ int edge_get(const int* __restrict__ e32, int i64, int e, int c){
  int idx = 2 * e + c;
  return i64 ? e32[2 * idx] : e32[idx];
}

// ---------------------------------------------------------------------------
// init_all: ONE dispatch.
//   blocks 0-3 : prep_w for mat=bx (self-detect fp32 flag)
//   block  4   : flags + zero desc[512] (lookback descriptors)
//   blocks 5+  : zero cnt[]
// ---------------------------------------------------------------------------
__global__ __launch_bounds__(256) void init_all(
    const void* __restrict__ Wq, const void* __restrict__ Wk,
    const void* __restrict__ Wv, const void* __restrict__ Wo,
    const void* __restrict__ bq, const void* __restrict__ bk,
    const void* __restrict__ bv, const void* __restrict__ bo,
    u16* __restrict__ Wt, float* __restrict__ biasP,
    const u16* __restrict__ lig16, const int* __restrict__ e32,
    int* __restrict__ flags, int* __restrict__ desc,
    int* __restrict__ cnt, int ntot)
{
  int bx = blockIdx.x, tid = threadIdx.x;

  if (bx < 4){
    __shared__ int Fsh;
    if (tid < 64){
      int c = 0;
      #pragma unroll
      for (int j = 0; j < 4; j++){
        u16 u = lig16[(tid * 4 + j) * 2];
        int ex = (u >> 7) & 0xFF;
        if (ex >= 96 && ex < 160) c++;
      }
      #pragma unroll
      for (int off = 1; off < 64; off <<= 1) c += __shfl_xor(c, off);
      if (tid == 0) Fsh = (c < 128) ? 1 : 0;
    }
    __syncthreads();
    int F = Fsh;
    int mat = bx;
    const void* W = (mat == 0) ? Wq : (mat == 1) ? Wk : (mat == 2) ? Wv : Wo;
    const void* b = (mat == 0) ? bq : (mat == 1) ? bk : (mat == 2) ? bv : bo;
    u16* dst = Wt + mat * 16384;
    #pragma unroll 4
    for (int j = 0; j < 64; j++){
      int idx = tid + j * 256;          // k = idx>>7, n = idx&127
      u16 w = F ? f2bf(((const float*)W)[idx]) : ((const u16*)W)[idx];
      dst[(idx & 127) * 128 + (idx >> 7)] = w;
    }
    if (tid < 128)
      biasP[mat * 128 + tid] = F ? ((const float*)b)[tid] : bf2f(((const u16*)b)[tid]);
  } else if (bx == 4){
    if (tid < 64){
      int c = 0, nz = 0;
      #pragma unroll
      for (int j = 0; j < 4; j++){
        u16 u = lig16[(tid * 4 + j) * 2];
        int ex = (u >> 7) & 0xFF;
        if (ex >= 96 && ex < 160) c++;
        if (e32[(tid * 4 + j) * 2 + 1] != 0) nz++;
      }
      #pragma unroll
      for (int off = 1; off < 64; off <<= 1){
        c  += __shfl_xor(c, off);
        nz += __shfl_xor(nz, off);
      }
      if (tid == 0){
        flags[0] = (c < 128) ? 1 : 0;
        flags[1] = (nz == 0) ? 1 : 0;
      }
    }
    desc[tid] = 0;                      // lookback descriptors: state 0 = invalid
    desc[256 + tid] = 0;
  } else {
    int i = (bx - 5) * 256 + tid;
    if (i < ntot) cnt[i] = 0;
  }
}

// ---------------------------------------------------------------------------
// edge_pre: RBF bias (ebias = attr@Wr + br) + degree count. Runs before QKV
// (degrees gate QKV tiles).
// ---------------------------------------------------------------------------
__global__ __launch_bounds__(256) void edge_pre(
    const void* __restrict__ attr, const void* __restrict__ Wr,
    const void* __restrict__ br, float* __restrict__ ebias,
    const int* __restrict__ edges, const int* __restrict__ ls_p,
    const int* __restrict__ ps_p, int* __restrict__ cnt, int nlig, int E_,
    const int* __restrict__ flags)
{
  __shared__ float w[16][8];
  __shared__ float b[8];
  int tid = threadIdx.x;
  int F = flags[0];
  if (tid < 128) w[tid >> 3][tid & 7] = F ? ((const float*)Wr)[tid] : bf2f(((const u16*)Wr)[tid]);
  if (tid < 8)   b[tid] = F ? ((const float*)br)[tid] : bf2f(((const u16*)br)[tid]);
  __syncthreads();
  int e = blockIdx.x * 256 + tid;
  if (e >= E_) return;

  int I64 = flags[1];
  int dl = edge_get(edges, I64, e, 0) - ls_p[0];
  int dp = edge_get(edges, I64, e, 1) - ps_p[0];
  atomicAdd(&cnt[dl], 1);
  atomicAdd(&cnt[nlig + dp], 1);

  float a[16];
  if (F){
    const float* af = (const float*)attr;
    #pragma unroll
    for (int j = 0; j < 4; j++){
      float4 t = *(const float4*)&af[e * 16 + j * 4];
      a[4*j] = t.x; a[4*j+1] = t.y; a[4*j+2] = t.z; a[4*j+3] = t.w;
    }
  } else {
    const u16* au = (const u16*)attr;
    #pragma unroll
    for (int j = 0; j < 4; j++){
      ushort4 t = *(const ushort4*)&au[e * 16 + j * 4];
      a[4*j] = bf2f(t.x); a[4*j+1] = bf2f(t.y); a[4*j+2] = bf2f(t.z); a[4*j+3] = bf2f(t.w);
    }
  }
  #pragma unroll
  for (int hh = 0; hh < 8; hh++){
    float s = b[hh];
    #pragma unroll
    for (int r = 0; r < 16; r++) s += a[r] * w[r][hh];
    ebias[e * 8 + hh] = s;
  }
}

// ---------------------------------------------------------------------------
// scan_lookback: standalone decoupled-lookback scan (rocPRIM pattern).
// 49 blocks x 2048 nodes; s_sleep backoff. R9: never fuse spinning consumers.
// ---------------------------------------------------------------------------
__global__ __launch_bounds__(256) void scan_lookback(
    const int* __restrict__ cnt, int* __restrict__ offs, int* __restrict__ cursor,
    int* __restrict__ desc, int n)
{
  __shared__ int lds[256];
  __shared__ int base_s;
  int bx = blockIdx.x, tid = threadIdx.x;
  int i0 = bx * 2048 + tid * 8;

  int v[8]; int s = 0;
  #pragma unroll
  for (int j = 0; j < 8; j++){
    int idx = i0 + j;
    v[j] = (idx < n) ? cnt[idx] : 0;
    s += v[j];
  }
  lds[tid] = s; __syncthreads();
  for (int off = 1; off < 256; off <<= 1){
    int t = (tid >= off) ? lds[tid - off] : 0;
    __syncthreads();
    lds[tid] += t;
    __syncthreads();
  }
  int thr_excl = lds[tid] - s;
  int block_sum = lds[255];

  if (tid == 0){
    if (bx == 0){
      __hip_atomic_store(&desc[0], (block_sum << 2) | 2, __ATOMIC_RELEASE,
                         __HIP_MEMORY_SCOPE_AGENT);
      base_s = 0;
    } else {
      __hip_atomic_store(&desc[bx], (block_sum << 2) | 1, __ATOMIC_RELEASE,
                         __HIP_MEMORY_SCOPE_AGENT);
      int running = 0;
      int idx = bx - 1;
      while (true){
        int d;
        while (((d = __hip_atomic_load(&desc[idx], __ATOMIC_ACQUIRE,
                                       __HIP_MEMORY_SCOPE_AGENT)) & 3) == 0){
          __builtin_amdgcn_s_sleep(1);
        }
        running += (d >> 2);
        if ((d & 3) == 2) break;
        idx--;
      }
      __hip_atomic_store(&desc[bx], ((running + block_sum) << 2) | 2,
                         __ATOMIC_RELEASE, __HIP_MEMORY_SCOPE_AGENT);
      base_s = running;
    }
  }
  __syncthreads();

  int base = base_s + thr_excl;
  #pragma unroll
  for (int j = 0; j < 8; j++){
    int idx = i0 + j;
    if (idx < n){
      offs[idx] = base;
      cursor[idx] = base;
      base += v[j];
      if (idx == n - 1) offs[n] = base;
    }
  }
}

// ---------------------------------------------------------------------------
// fat_qkv_sc: QKV projection with ACTIVITY SKIP + scatter, one dispatch.
//   Q role (TT 64-row tiles): skip tile if all rows degree-0 (R12-proven).
//   S role (eb blocks): scatter compact int2 {eid, src} (R13's 36-B inline
//   bias payload regressed: +32 MB random sub-line writes, fat 49->61 us).
// ---------------------------------------------------------------------------
__global__ __launch_bounds__(256) void fat_qkv_sc(
    const void* __restrict__ A0, int M0, const void* __restrict__ A1, int M1, int mb0,
    const u16* __restrict__ Wt, const float* __restrict__ biasP,
    u16* __restrict__ O0b, u16* __restrict__ O1b, u16* __restrict__ O2b,
    const int* __restrict__ offs,
    const int* __restrict__ edges, const int* __restrict__ ls_p,
    const int* __restrict__ ps_p, int* __restrict__ cursor,
    int2* __restrict__ sorted, int nlig, int E_, const int* __restrict__ flags)
{
  __shared__ __align__(16) char smem[34816];
  int tid = threadIdx.x;
  int F = flags[0];

  int TT = mb0 + ((M1 + 63) >> 6);
  int eb = (E_ + 255) >> 8;
  int G  = TT + eb;
  int bx = blockIdx.x;
  long long pp = (long long)bx * TT;
  int tile = (int)(pp / G);
  int isQ  = (int)(((long long)(bx + 1) * TT) / G) > tile;

  if (isQ){
    u16 (*As)[136] = (u16(*)[136])smem;
    u16 (*Fs)[136] = (u16(*)[136])(smem + 17408);
    __shared__ int act;
    int AF = F;                               // A dtype: 1=fp32, 0=bf16
    const void* A; int M, m0, orow;
    if (tile < mb0){ A = A0; M = M0; m0 = tile * 64;          orow = m0; }
    else           { A = A1; M = M1; m0 = (tile - mb0) * 64;  orow = M0 + m0; }

    // -------- activity check: any row in tile with degree > 0 ? --------
    if (tid == 0) act = 0;
    __syncthreads();
    if (tid < 64 && m0 + tid < M){
      int r = orow + tid;
      if (offs[r + 1] > offs[r]) act = 1;     // benign same-value race
    }
    __syncthreads();
    if (!act) return;                         // block-uniform exit

    if (AF){
      const float* Af = (const float*)A;
      #pragma unroll
      for (int j = 0; j < 8; j++){
        int u = tid + j * 256, row = u >> 5, c4 = (u & 31) * 4;
        float4 v = make_float4(0.f, 0.f, 0.f, 0.f);
        if (m0 + row < M) v = *(const float4*)&Af[(size_t)(m0 + row) * 128 + c4];
        ushort4 o; o.x = f2bf(v.x); o.y = f2bf(v.y); o.z = f2bf(v.z); o.w = f2bf(v.w);
        *(ushort4*)&As[row][c4] = o;
      }
    } else {
      const float4* Au = (const float4*)A;    // 16 B = 8 bf16
      #pragma unroll
      for (int j = 0; j < 4; j++){
        int u = tid + j * 256, row = u >> 4, c8 = (u & 15);
        float4 v = make_float4(0.f, 0.f, 0.f, 0.f);
        if (m0 + row < M) v = Au[(size_t)(m0 + row) * 16 + c8];
        *(float4*)&As[row][c8 * 8] = v;
      }
    }
    __syncthreads();

    int wave = tid >> 6, lane = tid & 63;
    int quad = lane >> 4, ml = lane & 15;

    for (int mat = 0; mat < 3; mat++){
      const u16* wp = Wt + (size_t)mat * 16384
                        + (size_t)(wave * 32 + ml) * 128 + quad * 8;
      short8 wf0[4], wf1[4];
      #pragma unroll
      for (int kk = 0; kk < 4; kk++){
        wf0[kk] = *(const short8*)&wp[kk * 32];
        wf1[kk] = *(const short8*)&wp[2048 + kk * 32];
      }
      float b0 = biasP[mat * 128 + wave * 32 + ml];
      float b1 = biasP[mat * 128 + wave * 32 + 16 + ml];

      f32x4 acc[4][2];
      #pragma unroll
      for (int mt = 0; mt < 4; mt++){
        acc[mt][0] = (f32x4){0.f, 0.f, 0.f, 0.f};
        acc[mt][1] = (f32x4){0.f, 0.f, 0.f, 0.f};
      }
      #pragma unroll
      for (int mt = 0; mt < 4; mt++){
        #pragma unroll
        for (int kk = 0; kk < 4; kk++){
          short8 af = *(const short8*)&As[mt * 16 + ml][kk * 32 + quad * 8];
          acc[mt][0] = __builtin_amdgcn_mfma_f32_16x16x32_bf16(af, wf0[kk], acc[mt][0], 0, 0, 0);
          acc[mt][1] = __builtin_amdgcn_mfma_f32_16x16x32_bf16(af, wf1[kk], acc[mt][1], 0, 0, 0);
        }
      }

      if (mat > 0) __syncthreads();           // prev mat's Fs store-reads done
      #pragma unroll
      for (int mt = 0; mt < 4; mt++){
        #pragma unroll
        for (int r = 0; r < 4; r++){
          int row = mt * 16 + quad * 4 + r;
          Fs[row][wave * 32 + ml]      = f2bf(acc[mt][0][r] + b0);
          Fs[row][wave * 32 + 16 + ml] = f2bf(acc[mt][1][r] + b1);
        }
      }
      __syncthreads();                        // Fs ready
      u16* Cb = (mat == 0) ? O0b : ((mat == 1) ? O1b : O2b);
      #pragma unroll
      for (int j = 0; j < 4; j++){
        int u = tid + j * 256, row = u >> 4, c8 = (u & 15) * 8;
        if (m0 + row < M)
          *(short8*)&Cb[(size_t)(orow + row) * 128 + c8] = *(const short8*)&Fs[row][c8];
      }
    }
  } else {
    // ---------------- scatter role (compact int2) ----------------
    int eidx = bx - tile;
    int e = eidx * 256 + tid;
    if (e >= E_) return;
    int I64 = flags[1];
    int dl = edge_get(edges, I64, e, 0) - ls_p[0];
    int dp = edge_get(edges, I64, e, 1) - ps_p[0];
    int p1 = atomicAdd(&cursor[dl], 1);        sorted[p1] = make_int2(e, nlig + dp);
    int p2 = atomicAdd(&cursor[nlig + dp], 1); sorted[p2] = make_int2(e, dl);
  }
}

// ---------------------------------------------------------------------------
// Attention v4: v2 structure (4 edges/wave via quarter-waves, 1 shfl/edge,
// pipelined gathers, butterfly merge) + R13's payload-independent wins:
//  - empty nodes return WITHOUT writing AGG (out_proj stages zeros)
//  - Q pre-scaled by SCALE at load
// Bias back to ebias[eid] gather (R12-measured; inline payload regressed).
// ---------------------------------------------------------------------------
__global__ __launch_bounds__(256) void attn_kernel(
    const u16* __restrict__ Q, const u16* __restrict__ K, const u16* __restrict__ V,
    const int2* __restrict__ sorted, const int* __restrict__ offs,
    const float* __restrict__ ebias, u16* __restrict__ AGG, int ntot)
{
  int t = blockIdx.x * 4 + (threadIdx.x >> 6);
  if (t >= ntot) return;
  int lane = threadIdx.x & 63;
  int ql = lane & 15;
  int q4 = lane >> 4;
  int h  = ql >> 1;

  int beg = offs[t], end = offs[t + 1];
  if (beg == end) return;                // no AGG write: out_proj zero-stages

  short8 qv = *(const short8*)&Q[(size_t)t * 128 + ql * 8];
  float qf[8];
  #pragma unroll
  for (int j = 0; j < 8; j++) qf[j] = bf2f((u16)qv[j]) * 0.25f;  // SCALE folded

  float m = -1e30f, l = 0.f;
  float a[8];
  #pragma unroll
  for (int j = 0; j < 8; j++) a[j] = 0.f;

  int i = beg + q4;
  int2 cur = make_int2(0, 0), nxt = make_int2(0, 0);
  if (i < end)     cur = sorted[i];
  if (i + 4 < end) nxt = sorted[i + 4];

  short8 kA = {0,0,0,0,0,0,0,0}, vA = {0,0,0,0,0,0,0,0};
  float ebA = 0.f;
  if (i < end){
    kA = *(const short8*)&K[(size_t)cur.y * 128 + ql * 8];
    vA = *(const short8*)&V[(size_t)cur.y * 128 + ql * 8];
    ebA = ebias[(size_t)cur.x * 8 + h];
  }

  while (i < end){
    short8 kB = {0,0,0,0,0,0,0,0}, vB = {0,0,0,0,0,0,0,0};
    float ebB = 0.f;
    if (i + 4 < end){
      kB = *(const short8*)&K[(size_t)nxt.y * 128 + ql * 8];
      vB = *(const short8*)&V[(size_t)nxt.y * 128 + ql * 8];
      ebB = ebias[(size_t)nxt.x * 8 + h];
    }
    int2 n2 = make_int2(0, 0);
    if (i + 8 < end) n2 = sorted[i + 8];

    float s = 0.f;
    #pragma unroll
    for (int j = 0; j < 8; j++) s += qf[j] * bf2f((u16)kA[j]);
    s += __shfl_xor(s, 1);               // pair-sum: full 16-dim head dot
    float logit = s + ebA;               // SCALE already folded into qf
    float nm = fmaxf(m, logit);
    float alpha = __expf(m - nm);
    float p = __expf(logit - nm);
    #pragma unroll
    for (int j = 0; j < 8; j++) a[j] = a[j] * alpha + p * bf2f((u16)vA[j]);
    l = l * alpha + p;
    m = nm;

    kA = kB; vA = vB; ebA = ebB;
    cur = nxt; nxt = n2;
    i += 4;
  }

  #pragma unroll
  for (int mask = 16; mask <= 32; mask <<= 1){
    float mo = __shfl_xor(m, mask);
    float lo = __shfl_xor(l, mask);
    float nm = fmaxf(m, mo);
    float sA = __expf(m - nm);
    float sB = __expf(mo - nm);
    l = l * sA + lo * sB;
    #pragma unroll
    for (int j = 0; j < 8; j++){
      float ao = __shfl_xor(a[j], mask);
      a[j] = a[j] * sA + ao * sB;
    }
    m = nm;
  }

  if (lane < 16){
    float inv = 1.f / (l + 1e-8f);
    short8 o;
    #pragma unroll
    for (int j = 0; j < 8; j++) o[j] = (short)f2bf(a[j] * inv);
    *(short8*)&AGG[(size_t)t * 128 + ql * 8] = o;
  }
}

// ---------------------------------------------------------------------------
// out_proj: AGG @ Wo + bo -> OUT. Bias-only fast path for fully-inactive
// tiles; mixed tiles stage ZEROS for degree-0 rows (attn does not write
// zero AGG rows). 64-row tiles, f32 direct store from accumulators.
// ---------------------------------------------------------------------------
__global__ __launch_bounds__(256) void out_proj(
    const u16* __restrict__ AGG, int M, const u16* __restrict__ Wt,
    const float* __restrict__ biasP, void* __restrict__ OUT,
    const int* __restrict__ offs, const int* __restrict__ flags)
{
  __shared__ __align__(16) u16 As[64][136];
  __shared__ __align__(16) u16 Fs[64][136];
  __shared__ int act;
  __shared__ int actRow[64];

  int tid = threadIdx.x;
  int F = flags[0];
  int m0 = blockIdx.x * 64;

  if (tid == 0) act = 0;
  __syncthreads();
  if (tid < 64){
    int r = m0 + tid;
    int a = (r < M) ? (offs[r + 1] > offs[r] ? 1 : 0) : 0;
    actRow[tid] = a;
    if (a) act = 1;                           // benign same-value race
  }
  __syncthreads();

  if (!act){
    // bias-only rows (out = bo exactly)
    if (F){
      float* Of = (float*)OUT;
      #pragma unroll
      for (int j = 0; j < 8; j++){
        int u = tid + j * 256, row = u >> 5, c4 = (u & 31) * 4;
        if (m0 + row < M)
          *(float4*)&Of[(size_t)(m0 + row) * 128 + c4] = *(const float4*)&biasP[384 + c4];
      }
    } else {
      u16* Ob = (u16*)OUT;
      #pragma unroll
      for (int j = 0; j < 4; j++){
        int u = tid + j * 256, row = u >> 4, c8 = (u & 15) * 8;
        if (m0 + row < M){
          short8 s8;
          #pragma unroll
          for (int k = 0; k < 8; k++) s8[k] = (short)f2bf(biasP[384 + c8 + k]);
          *(short8*)&Ob[(size_t)(m0 + row) * 128 + c8] = s8;
        }
      }
    }
    return;
  }

  // stage AGG tile (bf16); zero rows for degree-0 nodes
  {
    const float4* Au = (const float4*)AGG;
    #pragma unroll
    for (int j = 0; j < 4; j++){
      int u = tid + j * 256, row = u >> 4, c8 = (u & 15);
      float4 v = make_float4(0.f, 0.f, 0.f, 0.f);
      if (m0 + row < M && actRow[row]) v = Au[(size_t)(m0 + row) * 16 + c8];
      *(float4*)&As[row][c8 * 8] = v;
    }
  }
  __syncthreads();

  int wave = tid >> 6, lane = tid & 63;
  int quad = lane >> 4, ml = lane & 15;

  const u16* wp = Wt + (size_t)3 * 16384 + (size_t)(wave * 32 + ml) * 128 + quad * 8;
  short8 wf0[4], wf1[4];
  #pragma unroll
  for (int kk = 0; kk < 4; kk++){
    wf0[kk] = *(const short8*)&wp[kk * 32];
    wf1[kk] = *(const short8*)&wp[2048 + kk * 32];
  }
  float b0 = biasP[384 + wave * 32 + ml];
  float b1 = biasP[384 + wave * 32 + 16 + ml];

  f32x4 acc[4][2];
  #pragma unroll
  for (int mt = 0; mt < 4; mt++){
    acc[mt][0] = (f32x4){0.f, 0.f, 0.f, 0.f};
    acc[mt][1] = (f32x4){0.f, 0.f, 0.f, 0.f};
  }
  #pragma unroll
  for (int mt = 0; mt < 4; mt++){
    #pragma unroll
    for (int kk = 0; kk < 4; kk++){
      short8 af = *(const short8*)&As[mt * 16 + ml][kk * 32 + quad * 8];
      acc[mt][0] = __builtin_amdgcn_mfma_f32_16x16x32_bf16(af, wf0[kk], acc[mt][0], 0, 0, 0);
      acc[mt][1] = __builtin_amdgcn_mfma_f32_16x16x32_bf16(af, wf1[kk], acc[mt][1], 0, 0, 0);
    }
  }

  if (F){
    float* Of = (float*)OUT;
    #pragma unroll
    for (int mt = 0; mt < 4; mt++){
      #pragma unroll
      for (int r = 0; r < 4; r++){
        int row = mt * 16 + quad * 4 + r;
        if (m0 + row < M){
          float* op = &Of[(size_t)(m0 + row) * 128 + wave * 32 + ml];
          op[0]  = acc[mt][0][r] + b0;
          op[16] = acc[mt][1][r] + b1;
        }
      }
    }
  } else {
    #pragma unroll
    for (int mt = 0; mt < 4; mt++){
      #pragma unroll
      for (int r = 0; r < 4; r++){
        int row = mt * 16 + quad * 4 + r;
        Fs[row][wave * 32 + ml]      = f2bf(acc[mt][0][r] + b0);
        Fs[row][wave * 32 + 16 + ml] = f2bf(acc[mt][1][r] + b1);
      }
    }
    __syncthreads();
    u16* Ob = (u16*)OUT;
    #pragma unroll
    for (int j = 0; j < 4; j++){
      int u = tid + j * 256, row = u >> 4, c8 = (u & 15) * 8;
      if (m0 + row < M)
        *(short8*)&Ob[(size_t)(m0 + row) * 128 + c8] = *(const short8*)&Fs[row][c8];
    }
  }
}

// ---------------------------------------------------------------------------
extern "C" void kernel_launch(void* const* d_in, const int* in_sizes, int n_in,
                              void* d_out, int out_size, void* d_ws, size_t ws_size,
                              hipStream_t stream)
{
  const void* ligand_x  = d_in[0];
  const void* protein_x = d_in[1];
  const int* edges      = (const int*)d_in[2];
  const void* attr      = d_in[3];
  const void* Wq = d_in[4];  const void* bq = d_in[5];
  const void* Wk = d_in[6];  const void* bk = d_in[7];
  const void* Wv = d_in[8];  const void* bv = d_in[9];
  const void* Wo = d_in[10]; const void* bo = d_in[11];
  const void* Wr = d_in[12]; const void* br = d_in[13];
  const int* ls_p = (const int*)d_in[14];
  const int* ps_p = (const int*)d_in[15];

  const int nlig = in_sizes[0] / 128;
  const int nprot = in_sizes[1] / 128;
  const int E = in_sizes[2] / 2;
  const int ntot = nlig + nprot;

  char* w = (char*)d_ws;
  size_t off = 0;
  auto alloc = [&](size_t bytes) -> void* {
    void* p = w + off;
    off = (off + bytes + 255) & ~(size_t)255;
    return p;
  };
  int*   flags = (int*)alloc(256);
  u16*   Wt    = (u16*)alloc(4 * 16384 * 2);
  float* biasP = (float*)alloc(4 * 128 * 4);
  u16* Qb  = (u16*)alloc((size_t)ntot * 128 * 2);
  u16* Kb  = (u16*)alloc((size_t)ntot * 128 * 2);
  u16* Vb  = (u16*)alloc((size_t)ntot * 128 * 2);
  u16* AGG = (u16*)alloc((size_t)ntot * 128 * 2);
  float* ebias = (float*)alloc((size_t)E * 8 * 4);
  int* cnt    = (int*)alloc((size_t)ntot * 4);
  int* offs   = (int*)alloc((size_t)(ntot + 1) * 4);
  int* cursor = (int*)alloc((size_t)ntot * 4);
  int* desc   = (int*)alloc(512 * 4);
  int2* sorted = (int2*)alloc((size_t)2 * E * 8);
  (void)ws_size; (void)n_in; (void)out_size;

  const int mb_l = (nlig + 63) / 64;
  const int mb_p = (nprot + 63) / 64;
  const int mb_t = (ntot + 63) / 64;
  const int eb = (E + 255) / 256;
  const int nb = (ntot + 255) / 256;
  const int nsb = (ntot + 2047) / 2048;

  // 0. init: prep_w (self-detect) + flags + desc zero + cnt zero
  init_all<<<nb + 5, 256, 0, stream>>>(
      Wq, Wk, Wv, Wo, bq, bk, bv, bo, Wt, biasP,
      (const u16*)ligand_x, edges, flags, desc, cnt, ntot);

  // 1. edge_pre: RBF bias + degree count (degrees gate QKV tiles)
  edge_pre<<<eb, 256, 0, stream>>>(attr, Wr, br, ebias, edges, ls_p, ps_p,
                                   cnt, nlig, E, flags);

  // 2. decoupled-lookback scan -> offs/cursor
  scan_lookback<<<nsb, 256, 0, stream>>>(cnt, offs, cursor, desc, ntot);

  // 3. FAT: QKV (active tiles only) + scatter (compact int2)
  const int TT = mb_l + mb_p;
  fat_qkv_sc<<<TT + eb, 256, 0, stream>>>(
      ligand_x, nlig, protein_x, nprot, mb_l,
      Wt, biasP, Qb, Kb, Vb,
      offs, edges, ls_p, ps_p, cursor, sorted, nlig, E, flags);

  // 4. attention -> AGG (active nodes only)
  attn_kernel<<<(ntot + 3) / 4, 256, 0, stream>>>(
      Qb, Kb, Vb, sorted, offs, ebias, AGG, ntot);

  // 5. output projection (bias-only fast path; zero-stage degree-0 rows)
  out_proj<<<mb_t, 256, 0, stream>>>(AGG, ntot, Wt, biasP, d_out, offs, flags);
}